// Round 5
// baseline (349.388 us; speedup 1.0000x reference)
//
#include <hip/hip_runtime.h>
#include <hip/hip_bf16.h>

#define BB 16
#define CIN 256
#define COUT 256
#define HH 64
#define WW 64
#define SDIM 512

typedef __attribute__((ext_vector_type(8))) short bf16x8;
typedef __attribute__((ext_vector_type(4))) float f32x4;

static __device__ __forceinline__ short f2bf(float v) {
    __hip_bfloat16 h = __float2bfloat16(v);
    return *reinterpret_cast<short*>(&h);
}

// ---- kernel 1: wT[co][k][ci] bf16 + wsqT[ci][co] = sum_k w^2 (fp32) ----
__global__ void wprep_kernel(const float* __restrict__ w,
                             __hip_bfloat16* __restrict__ wT,
                             float* __restrict__ wsqT) {
    int co = blockIdx.x;   // 256
    int ci = threadIdx.x;  // 256
    const float* wp = w + ((size_t)co * CIN + ci) * 9;
    float q = 0.f;
#pragma unroll
    for (int k = 0; k < 9; ++k) {
        float v = wp[k];
        q += v * v;
        wT[((size_t)co * 9 + k) * CIN + ci] = __float2bfloat16(v);
    }
    wsqT[(size_t)ci * COUT + co] = q;
}

// ---- kernel 2: style projection s[b,ci] ----
__global__ void sproj_kernel(const float* __restrict__ style,
                             const float* __restrict__ style_w,
                             const float* __restrict__ style_b,
                             float* __restrict__ s) {
    int ci = threadIdx.x;
    int b  = blockIdx.x;
    float acc = style_b[ci];
    const float* st = style + b * SDIM;
#pragma unroll 4
    for (int sd = 0; sd < SDIM; ++sd)
        acc += st[sd] * style_w[sd * CIN + ci];
    s[b * CIN + ci] = acc;
}

// ---- kernel 3: fused modulated conv, bf16 MFMA, reg-prefetch pipeline ----
// block: 512 threads = 8 waves = 4 co-groups x 2 row-pairs
//        -> 128 co x 4 output rows x 64 px per block
// wave tile: 32 co x 2 rows x 64 px (2 m-tiles x 2 wr x 4 j of 16x16x32)
// LDS x-tile: [row6][quad4][col66][ci8] single buffer, 25344 B
__global__ __launch_bounds__(512, 4) void conv_mfma_kernel(
    const float* __restrict__ x, const __hip_bfloat16* __restrict__ wT,
    const float* __restrict__ s, const float* __restrict__ wsqT,
    float* __restrict__ out) {
    __shared__ __hip_bfloat16 xs[6 * 4 * 66 * 8];  // 25344 B
    __shared__ float s_lds[CIN];
    __shared__ float demod_lds[128];

    int tid  = threadIdx.x;
    int lane = tid & 63;
    int wave = tid >> 6;   // 0..7
    int cog  = wave >> 1;  // 0..3 : co group (32 co)
    int rp   = wave & 1;   // 0..1 : row pair
    int n    = lane & 15;
    int quad = lane >> 4;

    int Y0  = blockIdx.x * 4;        // 16 y-blocks
    int co0 = blockIdx.y * 128 + cog * 32;  // 2 co-blocks
    int b   = blockIdx.z;

    // load s into LDS; zero halo cols (0 and 65) once
    if (tid < CIN) s_lds[tid] = s[b * CIN + tid];
    if (tid < 48) {  // 24 (r,quad) units x 2 halo cols
        int u = tid >> 1, hc = (tid & 1) * 65;
        *(bf16x8*)(xs + ((u * 66) + hc) * 8) = (bf16x8){0, 0, 0, 0, 0, 0, 0, 0};
    }

    // ---- prefetch chunk 0 into registers (3 units/wave x 8 ch) ----
    float pf[3][8];
    int ur[3], uq[3];
#pragma unroll
    for (int i = 0; i < 3; ++i) {
        int u = wave * 3 + i;  // 24 units = 6 rows x 4 quads
        ur[i] = u >> 2;
        uq[i] = u & 3;
    }
#pragma unroll
    for (int i = 0; i < 3; ++i) {
        int y = Y0 - 1 + ur[i];
        if ((unsigned)y < (unsigned)HH) {
            const float* base =
                x + (((size_t)(b * CIN + uq[i] * 8)) * HH + y) * WW + lane;
#pragma unroll
            for (int c = 0; c < 8; ++c) pf[i][c] = base[(size_t)c * (HH * WW)];
        } else {
#pragma unroll
            for (int c = 0; c < 8; ++c) pf[i][c] = 0.f;
        }
    }
    __syncthreads();  // s_lds + halo zeros visible
    // write chunk 0
#pragma unroll
    for (int i = 0; i < 3; ++i) {
        bf16x8 wv;
#pragma unroll
        for (int c = 0; c < 8; ++c)
            wv[c] = f2bf(pf[i][c] * s_lds[uq[i] * 8 + c]);
        *(bf16x8*)(xs + (((ur[i] * 4 + uq[i]) * 66) + 1 + lane) * 8) = wv;
    }
    __syncthreads();

    f32x4 acc[2][2][4];  // [wr][m][j]
#pragma unroll
    for (int wr = 0; wr < 2; ++wr)
#pragma unroll
        for (int m = 0; m < 2; ++m)
#pragma unroll
            for (int j = 0; j < 4; ++j) acc[wr][m][j] = (f32x4){0.f, 0.f, 0.f, 0.f};

    const __hip_bfloat16* wb = wT + ((size_t)(co0 + n) * 9) * CIN + quad * 8;

    for (int cc = 0; cc < 8; ++cc) {
        // issue raw prefetch loads for cc+1 (held in regs until after MFMA)
        if (cc < 7) {
#pragma unroll
            for (int i = 0; i < 3; ++i) {
                int y = Y0 - 1 + ur[i];
                if ((unsigned)y < (unsigned)HH) {
                    const float* base =
                        x + (((size_t)(b * CIN + (cc + 1) * 32 + uq[i] * 8)) * HH + y) * WW + lane;
#pragma unroll
                    for (int c = 0; c < 8; ++c) pf[i][c] = base[(size_t)c * (HH * WW)];
                } else {
#pragma unroll
                    for (int c = 0; c < 8; ++c) pf[i][c] = 0.f;
                }
            }
        }

        bf16x8 af[2][9];
#pragma unroll
        for (int k = 0; k < 9; ++k) {
            af[0][k] = *(const bf16x8*)(wb + ((size_t)k) * CIN + cc * 32);
            af[1][k] = *(const bf16x8*)(wb + ((size_t)(16 * 9 + k)) * CIN + cc * 32);
        }

#pragma unroll
        for (int r4 = 0; r4 < 4; ++r4) {
            int rr = rp * 2 + r4;
#pragma unroll
            for (int dx = 0; dx < 3; ++dx) {
#pragma unroll
                for (int j = 0; j < 4; ++j) {
                    bf16x8 bv = *(const bf16x8*)(
                        xs + (((rr * 4 + quad) * 66) + j * 16 + n + dx) * 8);
                    if (r4 <= 2) {
                        acc[0][0][j] = __builtin_amdgcn_mfma_f32_16x16x32_bf16(
                            af[0][r4 * 3 + dx], bv, acc[0][0][j], 0, 0, 0);
                        acc[0][1][j] = __builtin_amdgcn_mfma_f32_16x16x32_bf16(
                            af[1][r4 * 3 + dx], bv, acc[0][1][j], 0, 0, 0);
                    }
                    if (r4 >= 1) {
                        acc[1][0][j] = __builtin_amdgcn_mfma_f32_16x16x32_bf16(
                            af[0][(r4 - 1) * 3 + dx], bv, acc[1][0][j], 0, 0, 0);
                        acc[1][1][j] = __builtin_amdgcn_mfma_f32_16x16x32_bf16(
                            af[1][(r4 - 1) * 3 + dx], bv, acc[1][1][j], 0, 0, 0);
                    }
                }
            }
        }

        if (cc < 7) {
            __syncthreads();  // all readers of xs done
#pragma unroll
            for (int i = 0; i < 3; ++i) {
                bf16x8 wv;
#pragma unroll
                for (int c = 0; c < 8; ++c)
                    wv[c] = f2bf(pf[i][c] * s_lds[(cc + 1) * 32 + uq[i] * 8 + c]);
                *(bf16x8*)(xs + (((ur[i] * 4 + uq[i]) * 66) + 1 + lane) * 8) = wv;
            }
            __syncthreads();  // writes visible
        }
    }

    // ---- inline demod: rp==0 waves compute demod for their 32 co ----
    __syncthreads();
    if (rp == 0 && lane < 32) {
        int co = co0 + lane;
        float d = 0.f;
#pragma unroll 4
        for (int ci = 0; ci < CIN; ++ci) {
            float sv = s_lds[ci];
            d += wsqT[(size_t)ci * COUT + co] * sv * sv;  // coalesced over lane
        }
        demod_lds[cog * 32 + lane] = rsqrtf(d * (1.0f / (CIN * 9)) + 1e-8f);
    }
    __syncthreads();

    // epilogue: C/D layout col=lane&15 (px), row=quad*4+reg (co)
    const float ms = 1.0f / 48.0f;
#pragma unroll
    for (int wr = 0; wr < 2; ++wr) {
        int gy = Y0 + rp * 2 + wr;
#pragma unroll
        for (int m = 0; m < 2; ++m) {
            int col = cog * 32 + m * 16 + quad * 4;  // local co in [0,128)
            int cobase = blockIdx.y * 128 + col;
            float d0 = demod_lds[col + 0] * ms;
            float d1 = demod_lds[col + 1] * ms;
            float d2 = demod_lds[col + 2] * ms;
            float d3 = demod_lds[col + 3] * ms;
#pragma unroll
            for (int j = 0; j < 4; ++j) {
                int gx = j * 16 + n;
                size_t o = ((size_t)(b * COUT + cobase) * HH + gy) * WW + gx;
                out[o]                       = acc[wr][m][j][0] * d0;
                out[o + (size_t)HH * WW]     = acc[wr][m][j][1] * d1;
                out[o + (size_t)2 * HH * WW] = acc[wr][m][j][2] * d2;
                out[o + (size_t)3 * HH * WW] = acc[wr][m][j][3] * d3;
            }
        }
    }
}

extern "C" void kernel_launch(void* const* d_in, const int* in_sizes, int n_in,
                              void* d_out, int out_size, void* d_ws, size_t ws_size,
                              hipStream_t stream) {
    const float* x       = (const float*)d_in[0];  // [16,256,64,64]
    const float* style   = (const float*)d_in[1];  // [16,512]
    const float* weight  = (const float*)d_in[2];  // [256,256,3,3]
    const float* style_w = (const float*)d_in[3];  // [512,256]
    const float* style_b = (const float*)d_in[4];  // [256]
    float* out = (float*)d_out;

    // ws: s[4096]f | wsqT[65536]f | wT[589824]bf16  (~1.5 MB)
    float* s    = (float*)d_ws;
    float* wsqT = s + BB * CIN;
    __hip_bfloat16* wT = (__hip_bfloat16*)(wsqT + COUT * CIN);

    wprep_kernel<<<COUT, CIN, 0, stream>>>(weight, wT, wsqT);
    sproj_kernel<<<BB, CIN, 0, stream>>>(style, style_w, style_b, s);
    conv_mfma_kernel<<<dim3(HH / 4, COUT / 128, BB), 512, 0, stream>>>(
        x, wT, s, wsqT, out);
}